// Round 12
// baseline (251.900 us; speedup 1.0000x reference)
//
#include <hip/hip_runtime.h>
#include <hip/hip_fp16.h>

#define TPB 256
#define CAP 16384          // slack entries per 256-node bucket (padded fill ~6000)
#define CAPSH 14           // log2(CAP)

typedef float    f32x4  __attribute__((ext_vector_type(4)));
typedef unsigned short u16x4 __attribute__((ext_vector_type(4)));

// z is stored feature-SPLIT: zlo[v] = 32 halves (features 0..31, 64 B),
// zhi[v] = features 32..63. Each 3.2 MB array fits the 4 MiB per-XCD L2, and
// layer_lo/layer_hi touch only one of them -> gather rows are L2 hits
// (~200 cyc) instead of L3 (~600 cyc). u = s@W partial (f32) is materialized
// between the two dispatches with nontemporal stores (no L2 pollution).
// Identity used: dis⊙(x@W) = (dis⊙x)@W and Agg(z@W) = (Agg z)@W.
// Buckets: 256 nodes (dst>>8); bucket b owns pairs/csr[b*CAP..). CSR runs
// padded to mult of 16 with index N (zero row). meta = {(off<<7)|nb, dis}.

__device__ __forceinline__ int ld_idx(const void* p, long long i, int is64) {
    return is64 ? (int)((const long long*)p)[i] : ((const int*)p)[i];
}

__device__ __forceinline__ ushort4 f4_to_h4(float4 v) {
    ushort4 r;
    r.x = __half_as_ushort(__float2half_rn(v.x));
    r.y = __half_as_ushort(__float2half_rn(v.y));
    r.z = __half_as_ushort(__float2half_rn(v.z));
    r.w = __half_as_ushort(__float2half_rn(v.w));
    return r;
}

__device__ __forceinline__ void nt_store_h4(ushort4* p, ushort4 v) {
    __builtin_nontemporal_store(*(u16x4*)&v, (u16x4*)p);
}

__device__ __forceinline__ void nt_store_f4(float4* p, float4 v) {
    __builtin_nontemporal_store(*(f32x4*)&v, (f32x4*)p);
}

// ---------------------------------------------------------------------------
// Scatter packed (src<<8 | dst&255) into per-bucket slack regions. gcur must
// be zeroed (hipMemsetAsync). Per-block edge-dtype detect.
// ---------------------------------------------------------------------------
__global__ __launch_bounds__(TPB) void p3_scatter(const void* ei, long long E,
                                                  int* gcur, int* pairs) {
    __shared__ int cnt[TPB];
    __shared__ int cur2[TPB];
    __shared__ int s_is64;
    int t = threadIdx.x;
    if (t < 64) {
        const unsigned int* w = (const unsigned int*)ei;
        unsigned long long m = __ballot(w[2 * t + 1] != 0u);
        if (t == 0) s_is64 = (m == 0ull) ? 1 : 0;
    }
    cnt[t] = 0;
    __syncthreads();
    const int is64 = s_is64;
    long long chunk = (E + gridDim.x - 1) / gridDim.x;
    long long s0 = (long long)blockIdx.x * chunk;
    long long s1 = (s0 + chunk < E) ? s0 + chunk : E;
    for (long long e = s0 + t; e < s1; e += TPB) {
        int d = ld_idx(ei, E + e, is64);
        atomicAdd(&cnt[d >> 8], 1);
    }
    __syncthreads();
    if (cnt[t]) cur2[t] = (t << CAPSH) + atomicAdd(&gcur[t], cnt[t]);
    __syncthreads();
    for (long long e = s0 + t; e < s1; e += TPB) {
        int sv = ld_idx(ei, e, is64);
        int d  = ld_idx(ei, E + e, is64);
        int pos = atomicAdd(&cur2[d >> 8], 1);
        pairs[pos] = (sv << 8) | (d & 255);
    }
}

// ---------------------------------------------------------------------------
// One block per bucket: degree count -> padded scan -> meta, csr scatter
// (+pad-to-16 with index N), then z0 = fp16(dis*x) split into zlo/zhi.
// ---------------------------------------------------------------------------
__global__ __launch_bounds__(TPB) void p4_fill(const int* __restrict__ pairs,
                                               const int* __restrict__ gcur,
                                               const float* __restrict__ x,
                                               int2* __restrict__ meta,
                                               int* __restrict__ csr,
                                               ushort4* __restrict__ zlo,
                                               ushort4* __restrict__ zhi, int N) {
    __shared__ int ldeg[TPB];
    __shared__ int ssc[TPB];
    __shared__ int cur[TPB];
    __shared__ float fdis[TPB];
    int t = threadIdx.x;
    int b = blockIdx.x;
    int base = b << CAPSH;
    int ecnt = gcur[b];                          // real edges in this bucket
    ldeg[t] = 0;
    __syncthreads();
    for (int e = base + t; e < base + ecnt; e += TPB)
        atomicAdd(&ldeg[pairs[e] & 255], 1);
    __syncthreads();
    int dv = ldeg[t];
    int pv = (dv + 15) & ~15;                    // padded to multiple of 16
    ssc[t] = pv;
    __syncthreads();
    for (int off = 1; off < TPB; off <<= 1) {
        int u = 0;
        if (t >= off) u = ssc[t - off];
        __syncthreads();
        ssc[t] += u;
        __syncthreads();
    }
    int o = base + ssc[t] - pv;                  // absolute padded offset
    cur[t] = o;
    float dd = rsqrtf((float)(dv + 1));          // +1 self loop
    fdis[t] = dd;
    int node = (b << 8) + t;
    if (node < N)
        meta[node] = make_int2((o << 7) | (pv >> 4), __float_as_int(dd));
    __syncthreads();
    for (int e = base + t; e < base + ecnt; e += TPB) {
        int p = pairs[e];
        int pos = atomicAdd(&cur[p & 255], 1);
        csr[pos] = p >> 8;
    }
    for (int e = o + dv; e < o + pv; ++e) csr[e] = N;   // pad with zero row

    // z0 conversion, split write: lane c<8 -> zlo chunk c, else zhi chunk c-8.
    int ni = t >> 4, c = t & 15;
    for (int p = 0; p < 16; ++p) {
        int nd = (b << 8) + p * 16 + ni;
        if (nd < N) {
            float dvv = fdis[p * 16 + ni];
            float4 h = ((const float4*)x)[(size_t)nd * 16 + c];
            float4 r = {h.x * dvv, h.y * dvv, h.z * dvv, h.w * dvv};
            ushort4 hv = f4_to_h4(r);
            if (c < 8) nt_store_h4(&zlo[(size_t)nd * 8 + c], hv);
            else       nt_store_h4(&zhi[(size_t)nd * 8 + (c - 8)], hv);
        }
    }
    if (b == 0 && t < 8)  nt_store_h4(&zlo[(size_t)N * 8 + t], make_ushort4(0,0,0,0));
    if (b == 0 && t >= 8 && t < 16)
        nt_store_h4(&zhi[(size_t)N * 8 + (t - 8)], make_ushort4(0,0,0,0));
}

// Cooperative gather on a HALF feature row (ushort2 = features 2c,2c+1 of the
// half): 16 lanes batch-load 16 CSR indices (nontemporal: csr lines are
// streamed, keep L2 for z), broadcast via __shfl, 16 independent 4B loads.
__device__ __forceinline__ float2 gather_half(const ushort2* __restrict__ z,
                                              const int* __restrict__ csr,
                                              int start, int nbatch, int c,
                                              float2 s) {
    const int base = threadIdx.x & 48;           // group base lane within wave
    for (int bt = 0; bt < nbatch; ++bt) {
        int idx = __builtin_nontemporal_load(csr + start + bt * 16 + c);
        #pragma unroll
        for (int k = 0; k < 16; ++k) {
            int si = __shfl(idx, base + k);
            ushort2 v = z[(size_t)si * 16 + c];
            s.x += __half2float(__ushort_as_half(v.x));
            s.y += __half2float(__ushort_as_half(v.y));
        }
    }
    return s;
}

// ---------------------------------------------------------------------------
// layer_lo: s_lo = zlo[v] + Agg zlo[src]; u = s_lo @ W[0:32,:] (f32 partial,
// nontemporal store). 16 nodes/block, 16 threads/node, W-half (8 KB) in LDS.
// ---------------------------------------------------------------------------
__global__ __launch_bounds__(TPB) void layer_lo(const ushort2* __restrict__ zlo,
                                                const int* __restrict__ csr,
                                                const int2* __restrict__ meta,
                                                const float* __restrict__ W,
                                                float4* __restrict__ u, int n) {
    __shared__ float Ws[32 * 64];                // W rows 0..31
    int t = threadIdx.x;
    float4* Ws4 = (float4*)Ws;
    const float4* W4g = (const float4*)W;
    Ws4[t] = W4g[t];
    Ws4[t + 256] = W4g[t + 256];

    int ni = t >> 4, c = t & 15;
    int node = blockIdx.x * 16 + ni;
    float2 s = {0.f, 0.f};
    if (node < n) {
        int2 m = meta[node];
        int start = ((unsigned)m.x) >> 7;
        int nbatch = m.x & 127;
        ushort2 v = zlo[(size_t)node * 16 + c];  // self-loop term
        s.x = __half2float(__ushort_as_half(v.x));
        s.y = __half2float(__ushort_as_half(v.y));
        s = gather_half(zlo, csr, start, nbatch, c, s);
    }
    __syncthreads();                             // Ws staged
    const int base = t & 48;
    float4 ua = {0.f, 0.f, 0.f, 0.f};
    #pragma unroll
    for (int q = 0; q < 16; ++q) {
        float a = __shfl(s.x, base + q);         // feature 2q
        float b = __shfl(s.y, base + q);         // feature 2q+1
        float4 w0 = Ws4[(2 * q) * 16 + c];
        float4 w1 = Ws4[(2 * q + 1) * 16 + c];
        ua.x = fmaf(a, w0.x, fmaf(b, w1.x, ua.x));
        ua.y = fmaf(a, w0.y, fmaf(b, w1.y, ua.y));
        ua.z = fmaf(a, w0.z, fmaf(b, w1.z, ua.z));
        ua.w = fmaf(a, w0.w, fmaf(b, w1.w, ua.w));
    }
    if (node < n) nt_store_f4(&u[(size_t)node * 16 + c], ua);
}

// ---------------------------------------------------------------------------
// layer_hi: s_hi = zhi[v] + Agg zhi[src]; u += s_hi @ W[32:64,:];
// z' = fp16(dis * relu(dis*u + b)), written feature-split (nt stores).
// ---------------------------------------------------------------------------
__global__ __launch_bounds__(TPB) void layer_hi(const ushort2* __restrict__ zhi,
                                                const int* __restrict__ csr,
                                                const int2* __restrict__ meta,
                                                const float* __restrict__ W,
                                                const float* __restrict__ b,
                                                const float4* __restrict__ u,
                                                ushort4* __restrict__ zolo,
                                                ushort4* __restrict__ zohi, int n) {
    __shared__ float Ws[32 * 64];                // W rows 32..63
    int t = threadIdx.x;
    float4* Ws4 = (float4*)Ws;
    const float4* W4g = (const float4*)W;
    Ws4[t] = W4g[512 + t];
    Ws4[t + 256] = W4g[768 + t];

    if (blockIdx.x == 0 && t < 8)                // zero row n for next layer
        nt_store_h4(&zolo[(size_t)n * 8 + t], make_ushort4(0,0,0,0));
    if (blockIdx.x == 0 && t >= 8 && t < 16)
        nt_store_h4(&zohi[(size_t)n * 8 + (t - 8)], make_ushort4(0,0,0,0));

    int ni = t >> 4, c = t & 15;
    int node = blockIdx.x * 16 + ni;
    float2 s = {0.f, 0.f};
    float dv = 0.f;
    if (node < n) {
        int2 m = meta[node];
        int start = ((unsigned)m.x) >> 7;
        int nbatch = m.x & 127;
        dv = __int_as_float(m.y);
        ushort2 v = zhi[(size_t)node * 16 + c];
        s.x = __half2float(__ushort_as_half(v.x));
        s.y = __half2float(__ushort_as_half(v.y));
        s = gather_half(zhi, csr, start, nbatch, c, s);
    }
    __syncthreads();
    const int base = t & 48;
    float4 ua = {0.f, 0.f, 0.f, 0.f};
    #pragma unroll
    for (int q = 0; q < 16; ++q) {
        float a = __shfl(s.x, base + q);         // feature 32+2q
        float bqv = __shfl(s.y, base + q);       // feature 33+2q
        float4 w0 = Ws4[(2 * q) * 16 + c];
        float4 w1 = Ws4[(2 * q + 1) * 16 + c];
        ua.x = fmaf(a, w0.x, fmaf(bqv, w1.x, ua.x));
        ua.y = fmaf(a, w0.y, fmaf(bqv, w1.y, ua.y));
        ua.z = fmaf(a, w0.z, fmaf(bqv, w1.z, ua.z));
        ua.w = fmaf(a, w0.w, fmaf(bqv, w1.w, ua.w));
    }
    if (node < n) {
        f32x4 up = __builtin_nontemporal_load((const f32x4*)&u[(size_t)node * 16 + c]);
        float4 bb = ((const float4*)b)[c];
        float4 r;
        r.x = fmaxf(fmaf(dv, ua.x + up.x, bb.x), 0.f) * dv;
        r.y = fmaxf(fmaf(dv, ua.y + up.y, bb.y), 0.f) * dv;
        r.z = fmaxf(fmaf(dv, ua.z + up.z, bb.z), 0.f) * dv;
        r.w = fmaxf(fmaf(dv, ua.w + up.w, bb.w), 0.f) * dv;
        ushort4 hv = f4_to_h4(r);
        if (c < 8) nt_store_h4(&zolo[(size_t)node * 8 + c], hv);
        else       nt_store_h4(&zohi[(size_t)node * 8 + (c - 8)], hv);
    }
}

// ---------------------------------------------------------------------------
// Final hi-kernel: h = relu(dis*(u_lo + s_hi@W2hi) + b2); out = h@linW + linb.
// ---------------------------------------------------------------------------
__global__ __launch_bounds__(TPB) void layer_hi_final(
        const ushort2* __restrict__ zhi, const int* __restrict__ csr,
        const int2* __restrict__ meta, const float* __restrict__ W,
        const float* __restrict__ b, const float4* __restrict__ u,
        const float* __restrict__ Wl, const float* __restrict__ bl,
        float* __restrict__ out, int n) {
    __shared__ float Ws[32 * 64];
    __shared__ float Wls[64 * 8];
    __shared__ float bls[8];
    int t = threadIdx.x;
    float4* Ws4 = (float4*)Ws;
    const float4* W4g = (const float4*)W;
    Ws4[t] = W4g[512 + t];
    Ws4[t + 256] = W4g[768 + t];
    if (t < 128) ((float4*)Wls)[t] = ((const float4*)Wl)[t];
    if (t < 8) bls[t] = bl[t];

    int ni = t >> 4, c = t & 15;
    int node = blockIdx.x * 16 + ni;
    float2 s = {0.f, 0.f};
    float dv = 0.f;
    if (node < n) {
        int2 m = meta[node];
        int start = ((unsigned)m.x) >> 7;
        int nbatch = m.x & 127;
        dv = __int_as_float(m.y);
        ushort2 v = zhi[(size_t)node * 16 + c];
        s.x = __half2float(__ushort_as_half(v.x));
        s.y = __half2float(__ushort_as_half(v.y));
        s = gather_half(zhi, csr, start, nbatch, c, s);
    }
    __syncthreads();
    const int base = t & 48;
    float4 ua = {0.f, 0.f, 0.f, 0.f};
    #pragma unroll
    for (int q = 0; q < 16; ++q) {
        float a = __shfl(s.x, base + q);
        float bqv = __shfl(s.y, base + q);
        float4 w0 = Ws4[(2 * q) * 16 + c];
        float4 w1 = Ws4[(2 * q + 1) * 16 + c];
        ua.x = fmaf(a, w0.x, fmaf(bqv, w1.x, ua.x));
        ua.y = fmaf(a, w0.y, fmaf(bqv, w1.y, ua.y));
        ua.z = fmaf(a, w0.z, fmaf(bqv, w1.z, ua.z));
        ua.w = fmaf(a, w0.w, fmaf(bqv, w1.w, ua.w));
    }
    f32x4 up = {0.f, 0.f, 0.f, 0.f};
    if (node < n)
        up = __builtin_nontemporal_load((const f32x4*)&u[(size_t)node * 16 + c]);
    float4 bb = ((const float4*)b)[c];
    float4 h;
    h.x = fmaxf(fmaf(dv, ua.x + up.x, bb.x), 0.f);
    h.y = fmaxf(fmaf(dv, ua.y + up.y, bb.y), 0.f);
    h.z = fmaxf(fmaf(dv, ua.z + up.z, bb.z), 0.f);
    h.w = fmaxf(fmaf(dv, ua.w + up.w, bb.w), 0.f);

    // second mm (64 -> 8): h lane c = output-features 4c..4c+3 of first mm.
    int col = c & 7;
    float acc = bls[col];
    #pragma unroll
    for (int r = 0; r < 4; ++r) {
        float hr = (r == 0) ? h.x : (r == 1) ? h.y : (r == 2) ? h.z : h.w;
        #pragma unroll
        for (int q = 0; q < 16; ++q) {
            float hv = __shfl(hr, base + q);     // feature q*4+r
            acc = fmaf(hv, Wls[(q * 4 + r) * 8 + col], acc);
        }
    }
    if (c < 8 && node < n) out[(size_t)node * 8 + col] = acc;
}

extern "C" void kernel_launch(void* const* d_in, const int* in_sizes, int n_in,
                              void* d_out, int out_size, void* d_ws, size_t ws_size,
                              hipStream_t stream) {
    const float* x  = (const float*)d_in[0];
    const void*  ei = d_in[1];
    const float* W0 = (const float*)d_in[2];
    const float* b0 = (const float*)d_in[3];
    const float* W1 = (const float*)d_in[4];
    const float* b1 = (const float*)d_in[5];
    const float* W2 = (const float*)d_in[6];
    const float* b2 = (const float*)d_in[7];
    const float* Wl = (const float*)d_in[8];
    const float* bl = (const float*)d_in[9];

    const long long E = in_sizes[1] / 2;                 // 800000
    const int dh = in_sizes[3];                          // 64
    const int din = in_sizes[2] / dh;                    // 64
    const int N = in_sizes[0] / din;                     // 50000
    const int nb = (N + 255) >> 8;                       // 196 buckets

    // Workspace carve (256-aligned): ~52 MB total
    char* ws = (char*)d_ws;
    size_t off = 0;
    auto alloc = [&](size_t bytes) -> char* {
        char* r = ws + off;
        off += (bytes + 255) & ~(size_t)255;
        return r;
    };
    int*     gcur  = (int*)    alloc(1024);
    int2*    meta  = (int2*)   alloc((size_t)N * 8);
    int*     pairs = (int*)    alloc((size_t)nb * CAP * 4);       // 12.8 MB
    int*     csr   = (int*)    alloc((size_t)nb * CAP * 4);       // 12.8 MB
    ushort4* zAlo  = (ushort4*)alloc((size_t)(N + 1) * 64);       // 3.2 MB each
    ushort4* zAhi  = (ushort4*)alloc((size_t)(N + 1) * 64);
    ushort4* zBlo  = (ushort4*)alloc((size_t)(N + 1) * 64);
    ushort4* zBhi  = (ushort4*)alloc((size_t)(N + 1) * 64);
    float4*  u     = (float4*) alloc((size_t)N * 256);            // 12.8 MB f32

    // --- preprocessing ---
    hipMemsetAsync(gcur, 0, 256 * sizeof(int), stream);
    p3_scatter<<<256, TPB, 0, stream>>>(ei, E, gcur, pairs);
    p4_fill<<<nb, TPB, 0, stream>>>(pairs, gcur, x, meta, csr, zAlo, zAhi, N);

    // --- 3 layers, each = lo-half + hi-half dispatch ---
    const int gL = (N + 15) / 16;                        // 3125
    layer_lo<<<gL, TPB, 0, stream>>>((const ushort2*)zAlo, csr, meta, W0, u, N);
    layer_hi<<<gL, TPB, 0, stream>>>((const ushort2*)zAhi, csr, meta, W0, b0, u,
                                     zBlo, zBhi, N);
    layer_lo<<<gL, TPB, 0, stream>>>((const ushort2*)zBlo, csr, meta, W1, u, N);
    layer_hi<<<gL, TPB, 0, stream>>>((const ushort2*)zBhi, csr, meta, W1, b1, u,
                                     zAlo, zAhi, N);
    layer_lo<<<gL, TPB, 0, stream>>>((const ushort2*)zAlo, csr, meta, W2, u, N);
    layer_hi_final<<<gL, TPB, 0, stream>>>((const ushort2*)zAhi, csr, meta, W2,
                                           b2, u, Wl, bl, (float*)d_out, N);
}

// Round 13
// 208.323 us; speedup vs baseline: 1.2092x; 1.2092x over previous
//
#include <hip/hip_runtime.h>
#include <hip/hip_fp16.h>

#define TPB 256
#define CAP 16384          // slack entries per 256-node bucket (padded fill ~6000)
#define CAPSH 14           // log2(CAP)
#define SC_BLOCKS 256      // scatter blocks
#define MAXE 16            // max edges per scatter thread (E<=TPB*SC_BLOCKS*MAXE)

// Identity used: dis⊙(x@W) = (dis⊙x)@W and Agg(z@W) = (Agg z)@W, so each
// layer is gather(z) -> mm -> relu, with z = fp16(dis ⊙ activation).
// Buckets: 256 nodes each (dst>>8). Bucket b owns pairs[b*CAP..) and
// csr[b*CAP..). CSR runs padded to a multiple of 16 with index N (zero row)
// -> uniform batch gather, no tail. meta[v] = {(off<<7)|nbatches, dis}.
// mm via __shfl broadcast (no LDS round-trip for s).
// R12 lesson: gather is latency-equilibrium-bound (~45us/layer) regardless of
// bytes/instructions/L2 residency -- keep the R11-proven shape (16 nodes/blk,
// 16 threads/node, high occupancy) and only shave preproc + chain latency.

__device__ __forceinline__ int ld_idx(const void* p, long long i, int is64) {
    return is64 ? (int)((const long long*)p)[i] : ((const int*)p)[i];
}

// fp16 row helpers: rows are 64 halves = 128 B = 16 x ushort4.
__device__ __forceinline__ float4 h4_to_f4(ushort4 v) {
    float4 r;
    r.x = __half2float(__ushort_as_half(v.x));
    r.y = __half2float(__ushort_as_half(v.y));
    r.z = __half2float(__ushort_as_half(v.z));
    r.w = __half2float(__ushort_as_half(v.w));
    return r;
}

__device__ __forceinline__ ushort4 f4_to_h4(float4 v) {
    ushort4 r;
    r.x = __half_as_ushort(__float2half_rn(v.x));
    r.y = __half_as_ushort(__float2half_rn(v.y));
    r.z = __half_as_ushort(__float2half_rn(v.z));
    r.w = __half_as_ushort(__float2half_rn(v.w));
    return r;
}

// ---------------------------------------------------------------------------
// SINGLE-PASS scatter: read each edge once, hold packed pairs in registers
// (MAXE unrolled -> stays in VGPRs), LDS histogram, one global atomic per
// non-empty (block,bucket), then register->global write-out.
// gcur must be zeroed (hipMemsetAsync). Per-block edge-dtype detect.
// ---------------------------------------------------------------------------
__global__ __launch_bounds__(TPB) void p3_scatter(const void* ei, long long E,
                                                  int* gcur, int* pairs) {
    __shared__ int cnt[TPB];
    __shared__ int cur2[TPB];
    __shared__ int s_is64;
    int t = threadIdx.x;
    if (t < 64) {
        const unsigned int* w = (const unsigned int*)ei;
        unsigned long long m = __ballot(w[2 * t + 1] != 0u);
        if (t == 0) s_is64 = (m == 0ull) ? 1 : 0;
    }
    cnt[t] = 0;
    __syncthreads();
    const int is64 = s_is64;
    long long chunk = (E + SC_BLOCKS - 1) / SC_BLOCKS;
    long long s0 = (long long)blockIdx.x * chunk;
    long long s1 = (s0 + chunk < E) ? s0 + chunk : E;

    int pk[MAXE];                                // (src<<8)|(dst&255)
    int bk[MAXE];                                // bucket = dst>>8
    int ne = 0;
    #pragma unroll
    for (int i = 0; i < MAXE; ++i) {
        long long e = s0 + t + (long long)i * TPB;
        if (e < s1) {
            int sv = ld_idx(ei, e, is64);
            int d  = ld_idx(ei, E + e, is64);
            pk[i] = (sv << 8) | (d & 255);
            bk[i] = d >> 8;
            atomicAdd(&cnt[bk[i]], 1);
            ne++;
        }
    }
    __syncthreads();
    if (cnt[t]) cur2[t] = (t << CAPSH) + atomicAdd(&gcur[t], cnt[t]);
    __syncthreads();
    #pragma unroll
    for (int i = 0; i < MAXE; ++i) {
        if (i < ne) {
            int pos = atomicAdd(&cur2[bk[i]], 1);
            pairs[pos] = pk[i];
        }
    }
}

// ---------------------------------------------------------------------------
// One block per bucket: degree count (LDS atomics) -> padded 256-wide scan
// -> meta, csr scatter via LDS cursors + pad-to-16 with index N, then
// z0 = fp16(dis * x) for this bucket's 256 nodes. Block 0 zeroes z0 row N.
// ---------------------------------------------------------------------------
__global__ __launch_bounds__(TPB) void p4_fill(const int* __restrict__ pairs,
                                               const int* __restrict__ gcur,
                                               const float* __restrict__ x,
                                               int2* __restrict__ meta,
                                               int* __restrict__ csr,
                                               ushort4* __restrict__ z0, int N) {
    __shared__ int ldeg[TPB];
    __shared__ int ssc[TPB];
    __shared__ int cur[TPB];
    __shared__ float fdis[TPB];
    int t = threadIdx.x;
    int b = blockIdx.x;
    int base = b << CAPSH;
    int ecnt = gcur[b];                          // real edges in this bucket
    ldeg[t] = 0;
    __syncthreads();
    for (int e = base + t; e < base + ecnt; e += TPB)
        atomicAdd(&ldeg[pairs[e] & 255], 1);
    __syncthreads();
    int dv = ldeg[t];
    int pv = (dv + 15) & ~15;                    // padded to multiple of 16
    ssc[t] = pv;
    __syncthreads();
    for (int off = 1; off < TPB; off <<= 1) {
        int u = 0;
        if (t >= off) u = ssc[t - off];
        __syncthreads();
        ssc[t] += u;
        __syncthreads();
    }
    int o = base + ssc[t] - pv;                  // absolute padded offset
    cur[t] = o;
    float dd = rsqrtf((float)(dv + 1));          // +1 self loop
    fdis[t] = dd;
    int node = (b << 8) + t;
    if (node < N)
        meta[node] = make_int2((o << 7) | (pv >> 4), __float_as_int(dd));
    __syncthreads();
    for (int e = base + t; e < base + ecnt; e += TPB) {
        int p = pairs[e];
        int pos = atomicAdd(&cur[p & 255], 1);
        csr[pos] = p >> 8;
    }
    for (int e = o + dv; e < o + pv; ++e) csr[e] = N;   // pad with zero row

    // z0 conversion: 16 passes, 16 nodes each, coalesced float4 reads.
    int ni = t >> 4, c = t & 15;
    for (int p = 0; p < 16; ++p) {
        int nd = (b << 8) + p * 16 + ni;
        if (nd < N) {
            float dvv = fdis[p * 16 + ni];
            float4 h = ((const float4*)x)[(size_t)nd * 16 + c];
            float4 r = {h.x * dvv, h.y * dvv, h.z * dvv, h.w * dvv};
            z0[(size_t)nd * 16 + c] = f4_to_h4(r);
        }
    }
    if (b == 0 && t < 16) z0[(size_t)N * 16 + t] = make_ushort4(0, 0, 0, 0);
}

// Cooperative gather (fp16 rows, PADDED csr): 16 lanes batch-load 16 CSR
// indices in one coalesced read, broadcast via __shfl, 16 INDEPENDENT 8B
// row-chunk loads. Next batch's idx is PREFETCHED so the idx-load ->
// bpermute -> row-load chain of batch bt+1 overlaps batch bt's row loads.
__device__ __forceinline__ float4 gather_rows(const ushort4* __restrict__ y4,
                                              const int* __restrict__ csr,
                                              int start, int nbatch, int c,
                                              float4 acc) {
    const int base = threadIdx.x & 48;           // group base lane within wave
    int idx = (nbatch > 0) ? csr[start + c] : 0;
    for (int bt = 0; bt < nbatch; ++bt) {
        int nidx = (bt + 1 < nbatch) ? csr[start + (bt + 1) * 16 + c] : 0;
        #pragma unroll
        for (int k = 0; k < 16; ++k) {
            int s = __shfl(idx, base + k);
            float4 v = h4_to_f4(y4[(size_t)s * 16 + c]);
            acc.x += v.x; acc.y += v.y; acc.z += v.z; acc.w += v.w;
        }
        idx = nidx;
    }
    return acc;
}

// Shfl-based mm: s (cols 4c..4c+3 of its node) is distributed across the 16
// lanes of the group; broadcast via __shfl instead of an LDS round-trip.
__device__ __forceinline__ float4 shfl_mm(float4 s, const float4* Ws4, int c) {
    const int base = threadIdx.x & 48;
    float4 u = {0.f, 0.f, 0.f, 0.f};
    #pragma unroll
    for (int r = 0; r < 4; ++r) {
        float sr = (r == 0) ? s.x : (r == 1) ? s.y : (r == 2) ? s.z : s.w;
        #pragma unroll
        for (int q = 0; q < 16; ++q) {
            float hv = __shfl(sr, base + q);     // s[node][q*4+r]
            float4 w = Ws4[(q * 4 + r) * 16 + c];
            u.x = fmaf(hv, w.x, u.x);
            u.y = fmaf(hv, w.y, u.y);
            u.z = fmaf(hv, w.z, u.z);
            u.w = fmaf(hv, w.w, u.w);
        }
    }
    return u;
}

// ---------------------------------------------------------------------------
// Layer: s = z_v + Agg z_u (gather); u = s @ W; zout = fp16(dis*relu(dis*u+b)).
// 16 nodes/block, 16 threads/node. Only W in LDS (16 KB).
// ---------------------------------------------------------------------------
__global__ __launch_bounds__(TPB) void layer_mm(const ushort4* __restrict__ z,
                                                const int* __restrict__ csr,
                                                const int2* __restrict__ meta,
                                                const float* __restrict__ b,
                                                const float* __restrict__ W,
                                                ushort4* __restrict__ zout, int n) {
    __shared__ float Ws[64 * 64];
    int t = threadIdx.x;
    float4* Ws4 = (float4*)Ws;
    const float4* W4g = (const float4*)W;
    #pragma unroll
    for (int i = 0; i < 4; ++i) Ws4[t + i * TPB] = W4g[t + i * TPB];

    if (blockIdx.x == 0 && t < 16)               // zero row N for next layer
        zout[(size_t)n * 16 + t] = make_ushort4(0, 0, 0, 0);

    int ni = t >> 4, c = t & 15;
    int node = blockIdx.x * 16 + ni;
    float4 s = {0.f, 0.f, 0.f, 0.f};
    float dv = 0.f;
    if (node < n) {
        int2 m = meta[node];
        int start = ((unsigned)m.x) >> 7;
        int nbatch = m.x & 127;
        dv = __int_as_float(m.y);
        s = h4_to_f4(z[(size_t)node * 16 + c]);  // self-loop term z_v
        s = gather_rows(z, csr, start, nbatch, c, s);
    }
    __syncthreads();                             // Ws fully staged
    float4 u = shfl_mm(s, Ws4, c);
    if (node < n) {
        float4 bb = ((const float4*)b)[c];
        float4 r;
        r.x = fmaxf(fmaf(dv, u.x, bb.x), 0.f) * dv;
        r.y = fmaxf(fmaf(dv, u.y, bb.y), 0.f) * dv;
        r.z = fmaxf(fmaf(dv, u.z, bb.z), 0.f) * dv;
        r.w = fmaxf(fmaf(dv, u.w, bb.w), 0.f) * dv;
        zout[(size_t)node * 16 + c] = f4_to_h4(r);   // z_{l+1}
    }
}

// ---------------------------------------------------------------------------
// Final: s = gather(z2); h = relu(dis*(s@W2)+b2); out = h @ linW + linb.
// Both mms via shfl broadcast.
// ---------------------------------------------------------------------------
__global__ __launch_bounds__(TPB) void layer_final(const ushort4* __restrict__ z,
                                                   const int* __restrict__ csr,
                                                   const int2* __restrict__ meta,
                                                   const float* __restrict__ b,
                                                   const float* __restrict__ W,
                                                   const float* __restrict__ Wl,
                                                   const float* __restrict__ bl,
                                                   float* __restrict__ out, int n) {
    __shared__ float Ws[64 * 64];
    __shared__ float Wls[64 * 8];
    __shared__ float bls[8];
    int t = threadIdx.x;
    float4* Ws4 = (float4*)Ws;
    const float4* W4g = (const float4*)W;
    #pragma unroll
    for (int i = 0; i < 4; ++i) Ws4[t + i * TPB] = W4g[t + i * TPB];
    if (t < 128) ((float4*)Wls)[t] = ((const float4*)Wl)[t];
    if (t < 8) bls[t] = bl[t];

    int ni = t >> 4, c = t & 15;
    int node = blockIdx.x * 16 + ni;
    float4 s = {0.f, 0.f, 0.f, 0.f};
    float dv = 0.f;
    if (node < n) {
        int2 m = meta[node];
        int start = ((unsigned)m.x) >> 7;
        int nbatch = m.x & 127;
        dv = __int_as_float(m.y);
        s = h4_to_f4(z[(size_t)node * 16 + c]);
        s = gather_rows(z, csr, start, nbatch, c, s);
    }
    __syncthreads();                             // Ws/Wls/bls staged
    float4 u = shfl_mm(s, Ws4, c);
    float4 bb = ((const float4*)b)[c];
    float4 h;
    h.x = fmaxf(fmaf(dv, u.x, bb.x), 0.f);
    h.y = fmaxf(fmaf(dv, u.y, bb.y), 0.f);
    h.z = fmaxf(fmaf(dv, u.z, bb.z), 0.f);
    h.w = fmaxf(fmaf(dv, u.w, bb.w), 0.f);

    // second mm (64 -> 8) via shfl: lane c<8 computes output col c.
    const int base = threadIdx.x & 48;
    int col = c & 7;
    float acc = bls[col];
    #pragma unroll
    for (int r = 0; r < 4; ++r) {
        float hr = (r == 0) ? h.x : (r == 1) ? h.y : (r == 2) ? h.z : h.w;
        #pragma unroll
        for (int q = 0; q < 16; ++q) {
            float hv = __shfl(hr, base + q);     // feature q*4+r
            acc = fmaf(hv, Wls[(q * 4 + r) * 8 + col], acc);
        }
    }
    if (c < 8 && node < n) out[(size_t)node * 8 + col] = acc;
}

extern "C" void kernel_launch(void* const* d_in, const int* in_sizes, int n_in,
                              void* d_out, int out_size, void* d_ws, size_t ws_size,
                              hipStream_t stream) {
    const float* x  = (const float*)d_in[0];
    const void*  ei = d_in[1];
    const float* W0 = (const float*)d_in[2];
    const float* b0 = (const float*)d_in[3];
    const float* W1 = (const float*)d_in[4];
    const float* b1 = (const float*)d_in[5];
    const float* W2 = (const float*)d_in[6];
    const float* b2 = (const float*)d_in[7];
    const float* Wl = (const float*)d_in[8];
    const float* bl = (const float*)d_in[9];

    const long long E = in_sizes[1] / 2;                 // 800000
    const int dh = in_sizes[3];                          // 64
    const int din = in_sizes[2] / dh;                    // 64
    const int N = in_sizes[0] / din;                     // 50000
    const int nb = (N + 255) >> 8;                       // 196 buckets

    // Workspace carve (256-aligned): ~39 MB total
    char* ws = (char*)d_ws;
    size_t off = 0;
    auto alloc = [&](size_t bytes) -> char* {
        char* r = ws + off;
        off += (bytes + 255) & ~(size_t)255;
        return r;
    };
    int*     gcur    = (int*)    alloc(1024);
    int2*    meta    = (int2*)   alloc((size_t)N * 8);
    int*     pairs   = (int*)    alloc((size_t)nb * CAP * 4);     // 12.8 MB
    int*     csr     = (int*)    alloc((size_t)nb * CAP * 4);     // 12.8 MB
    ushort4* zbA     = (ushort4*)alloc((size_t)(N + 1) * 64 * 2); // fp16 rows (+zero row)
    ushort4* zbB     = (ushort4*)alloc((size_t)(N + 1) * 64 * 2);

    // --- preprocessing ---
    hipMemsetAsync(gcur, 0, 256 * sizeof(int), stream);
    p3_scatter<<<SC_BLOCKS, TPB, 0, stream>>>(ei, E, gcur, pairs);
    p4_fill<<<nb, TPB, 0, stream>>>(pairs, gcur, x, meta, csr, zbA, N);

    // --- 3 layers: gather -> mm -> relu ---
    const int gL = (N + 15) / 16;                        // 3125
    layer_mm<<<gL, TPB, 0, stream>>>(zbA, csr, meta, b0, W0, zbB, N);
    layer_mm<<<gL, TPB, 0, stream>>>(zbB, csr, meta, b1, W1, zbA, N);
    layer_final<<<gL, TPB, 0, stream>>>(zbA, csr, meta, b2, W2, Wl, bl,
                                        (float*)d_out, N);
}

// Round 14
// 185.388 us; speedup vs baseline: 1.3588x; 1.1237x over previous
//
#include <hip/hip_runtime.h>
#include <hip/hip_fp16.h>

#define TPB 256
#define CAP 16384          // slack entries per 256-node bucket (padded fill ~5100)
#define CAPSH 14           // log2(CAP)
#define SC_BLOCKS 256      // scatter blocks
#define MAXE 16            // max edges per scatter thread (E<=TPB*SC_BLOCKS*MAXE)

typedef __attribute__((ext_vector_type(8))) float f32x8;
typedef __attribute__((ext_vector_type(8))) unsigned short u16x8;

// Identity used: dis⊙(x@W) = (dis⊙x)@W and Agg(z@W) = (Agg z)@W, so each
// layer is gather(z) -> mm -> relu, with z = fp16(dis ⊙ activation).
// Buckets: 256 nodes each (dst>>8); bucket b owns pairs/csr[b*CAP..).
// CSR runs padded to a multiple of 8 (was 16: avg degree 16 -> pad tax
// halves, 385k -> 190k phantom gathers) with index N (zero row).
// meta[v] = { (offset<<8) | nbatches, bitcast(dis) }.
// Layer kernels: 8 threads/node, ushort8 = 16 B row chunks (coalescing sweet
// spot): load+shfl count per row halves; rows-in-flight per wave unchanged
// (8 groups x 8 = 64) so the latency equilibrium is preserved.

__device__ __forceinline__ int ld_idx(const void* p, long long i, int is64) {
    return is64 ? (int)((const long long*)p)[i] : ((const int*)p)[i];
}

__device__ __forceinline__ ushort4 f4_to_h4(float4 v) {
    ushort4 r;
    r.x = __half_as_ushort(__float2half_rn(v.x));
    r.y = __half_as_ushort(__float2half_rn(v.y));
    r.z = __half_as_ushort(__float2half_rn(v.z));
    r.w = __half_as_ushort(__float2half_rn(v.w));
    return r;
}

// ---------------------------------------------------------------------------
// SINGLE-PASS scatter: read each edge once, hold packed pairs in registers,
// LDS histogram, one global atomic per non-empty (block,bucket), write out.
// gcur must be zeroed (hipMemsetAsync). Per-block edge-dtype detect.
// ---------------------------------------------------------------------------
__global__ __launch_bounds__(TPB) void p3_scatter(const void* ei, long long E,
                                                  int* gcur, int* pairs) {
    __shared__ int cnt[TPB];
    __shared__ int cur2[TPB];
    __shared__ int s_is64;
    int t = threadIdx.x;
    if (t < 64) {
        const unsigned int* w = (const unsigned int*)ei;
        unsigned long long m = __ballot(w[2 * t + 1] != 0u);
        if (t == 0) s_is64 = (m == 0ull) ? 1 : 0;
    }
    cnt[t] = 0;
    __syncthreads();
    const int is64 = s_is64;
    long long chunk = (E + SC_BLOCKS - 1) / SC_BLOCKS;
    long long s0 = (long long)blockIdx.x * chunk;
    long long s1 = (s0 + chunk < E) ? s0 + chunk : E;

    int pk[MAXE];                                // (src<<8)|(dst&255)
    int bk[MAXE];                                // bucket = dst>>8
    int ne = 0;
    #pragma unroll
    for (int i = 0; i < MAXE; ++i) {
        long long e = s0 + t + (long long)i * TPB;
        if (e < s1) {
            int sv = ld_idx(ei, e, is64);
            int d  = ld_idx(ei, E + e, is64);
            pk[i] = (sv << 8) | (d & 255);
            bk[i] = d >> 8;
            atomicAdd(&cnt[bk[i]], 1);
            ne++;
        }
    }
    __syncthreads();
    if (cnt[t]) cur2[t] = (t << CAPSH) + atomicAdd(&gcur[t], cnt[t]);
    __syncthreads();
    #pragma unroll
    for (int i = 0; i < MAXE; ++i) {
        if (i < ne) {
            int pos = atomicAdd(&cur2[bk[i]], 1);
            pairs[pos] = pk[i];
        }
    }
}

// ---------------------------------------------------------------------------
// One block per bucket: degree count (LDS atomics) -> pad-to-8 256-wide scan
// -> meta, csr scatter via LDS cursors + pad with index N, then
// z0 = fp16(dis * x) for this bucket's 256 nodes. Block 0 zeroes z0 row N.
// ---------------------------------------------------------------------------
__global__ __launch_bounds__(TPB) void p4_fill(const int* __restrict__ pairs,
                                               const int* __restrict__ gcur,
                                               const float* __restrict__ x,
                                               int2* __restrict__ meta,
                                               int* __restrict__ csr,
                                               ushort4* __restrict__ z0, int N) {
    __shared__ int ldeg[TPB];
    __shared__ int ssc[TPB];
    __shared__ int cur[TPB];
    __shared__ float fdis[TPB];
    int t = threadIdx.x;
    int b = blockIdx.x;
    int base = b << CAPSH;
    int ecnt = gcur[b];                          // real edges in this bucket
    ldeg[t] = 0;
    __syncthreads();
    for (int e = base + t; e < base + ecnt; e += TPB)
        atomicAdd(&ldeg[pairs[e] & 255], 1);
    __syncthreads();
    int dv = ldeg[t];
    int pv = (dv + 7) & ~7;                      // padded to multiple of 8
    ssc[t] = pv;
    __syncthreads();
    for (int off = 1; off < TPB; off <<= 1) {
        int u = 0;
        if (t >= off) u = ssc[t - off];
        __syncthreads();
        ssc[t] += u;
        __syncthreads();
    }
    int o = base + ssc[t] - pv;                  // absolute padded offset
    cur[t] = o;
    float dd = rsqrtf((float)(dv + 1));          // +1 self loop
    fdis[t] = dd;
    int node = (b << 8) + t;
    if (node < N)
        meta[node] = make_int2((o << 8) | (pv >> 3), __float_as_int(dd));
    __syncthreads();
    for (int e = base + t; e < base + ecnt; e += TPB) {
        int p = pairs[e];
        int pos = atomicAdd(&cur[p & 255], 1);
        csr[pos] = p >> 8;
    }
    for (int e = o + dv; e < o + pv; ++e) csr[e] = N;   // pad with zero row

    // z0 conversion: 16 passes, 16 nodes each, coalesced float4 reads.
    int ni = t >> 4, c = t & 15;
    for (int p = 0; p < 16; ++p) {
        int nd = (b << 8) + p * 16 + ni;
        if (nd < N) {
            float dvv = fdis[p * 16 + ni];
            float4 h = ((const float4*)x)[(size_t)nd * 16 + c];
            float4 r = {h.x * dvv, h.y * dvv, h.z * dvv, h.w * dvv};
            z0[(size_t)nd * 16 + c] = f4_to_h4(r);
        }
    }
    if (b == 0 && t < 16) z0[(size_t)N * 16 + t] = make_ushort4(0, 0, 0, 0);
}

// Cooperative gather (fp16 rows as ushort8 = 16 B chunks, PADDED csr):
// 8 lanes batch-load 8 CSR indices in one coalesced read, broadcast via
// __shfl, 8 INDEPENDENT 16B row-chunk loads. Next batch's idx prefetched.
__device__ __forceinline__ f32x8 gather_rows(const u16x8* __restrict__ z8,
                                             const int* __restrict__ csr,
                                             int start, int nbatch, int c,
                                             f32x8 acc) {
    const int base = threadIdx.x & 56;           // 8-lane group base in wave
    int idx = (nbatch > 0) ? csr[start + c] : 0;
    for (int bt = 0; bt < nbatch; ++bt) {
        int nidx = (bt + 1 < nbatch) ? csr[start + (bt + 1) * 8 + c] : 0;
        #pragma unroll
        for (int k = 0; k < 8; ++k) {
            int s = __shfl(idx, base + k);
            u16x8 v = z8[(size_t)s * 8 + c];
            #pragma unroll
            for (int i = 0; i < 8; ++i)
                acc[i] += __half2float(__ushort_as_half(v[i]));
        }
        idx = nidx;
    }
    return acc;
}

// Shfl-based mm for 8-lane groups: lane c holds features 8c..8c+7 of its
// node (f32x8); broadcast via __shfl; lane c accumulates output cols
// 8c..8c+7. Per-k Ws reads are 2 consecutive float4s (256 B/group contiguous,
// broadcast across groups -> conflict-free).
__device__ __forceinline__ f32x8 shfl_mm8(f32x8 s, const float4* Ws4, int c) {
    const int base = threadIdx.x & 56;
    f32x8 u = {0.f, 0.f, 0.f, 0.f, 0.f, 0.f, 0.f, 0.f};
    #pragma unroll
    for (int q = 0; q < 8; ++q) {
        #pragma unroll
        for (int r = 0; r < 8; ++r) {
            float hv = __shfl(s[r], base + q);   // feature q*8+r
            float4 w0 = Ws4[(q * 8 + r) * 16 + 2 * c];
            float4 w1 = Ws4[(q * 8 + r) * 16 + 2 * c + 1];
            u[0] = fmaf(hv, w0.x, u[0]);
            u[1] = fmaf(hv, w0.y, u[1]);
            u[2] = fmaf(hv, w0.z, u[2]);
            u[3] = fmaf(hv, w0.w, u[3]);
            u[4] = fmaf(hv, w1.x, u[4]);
            u[5] = fmaf(hv, w1.y, u[5]);
            u[6] = fmaf(hv, w1.z, u[6]);
            u[7] = fmaf(hv, w1.w, u[7]);
        }
    }
    return u;
}

__device__ __forceinline__ u16x8 f8_to_h8(f32x8 v) {
    u16x8 r;
    #pragma unroll
    for (int i = 0; i < 8; ++i)
        r[i] = __half_as_ushort(__float2half_rn(v[i]));
    return r;
}

// ---------------------------------------------------------------------------
// Layer: s = z_v + Agg z_u (gather); u = s @ W; zout = fp16(dis*relu(dis*u+b)).
// 32 nodes/block, 8 threads/node. Only W in LDS (16 KB).
// ---------------------------------------------------------------------------
__global__ __launch_bounds__(TPB) void layer_mm(const u16x8* __restrict__ z,
                                                const int* __restrict__ csr,
                                                const int2* __restrict__ meta,
                                                const float* __restrict__ b,
                                                const float* __restrict__ W,
                                                u16x8* __restrict__ zout, int n) {
    __shared__ float Ws[64 * 64];
    int t = threadIdx.x;
    float4* Ws4 = (float4*)Ws;
    const float4* W4g = (const float4*)W;
    #pragma unroll
    for (int i = 0; i < 4; ++i) Ws4[t + i * TPB] = W4g[t + i * TPB];

    if (blockIdx.x == 0 && t < 8) {              // zero row N for next layer
        u16x8 zz = {0, 0, 0, 0, 0, 0, 0, 0};
        zout[(size_t)n * 8 + t] = zz;
    }

    int wave = t >> 6, lane = t & 63;
    int g = lane >> 3, c = lane & 7;
    int node = blockIdx.x * 32 + wave * 8 + g;
    f32x8 s = {0.f, 0.f, 0.f, 0.f, 0.f, 0.f, 0.f, 0.f};
    float dv = 0.f;
    if (node < n) {
        int2 m = meta[node];
        int start = ((unsigned)m.x) >> 8;
        int nbatch = m.x & 255;
        dv = __int_as_float(m.y);
        u16x8 v = z[(size_t)node * 8 + c];       // self-loop term z_v
        #pragma unroll
        for (int i = 0; i < 8; ++i) s[i] = __half2float(__ushort_as_half(v[i]));
        s = gather_rows(z, csr, start, nbatch, c, s);
    }
    __syncthreads();                             // Ws fully staged
    f32x8 u = shfl_mm8(s, Ws4, c);
    if (node < n) {
        float4 b0 = ((const float4*)b)[2 * c];
        float4 b1 = ((const float4*)b)[2 * c + 1];
        f32x8 r;
        r[0] = fmaxf(fmaf(dv, u[0], b0.x), 0.f) * dv;
        r[1] = fmaxf(fmaf(dv, u[1], b0.y), 0.f) * dv;
        r[2] = fmaxf(fmaf(dv, u[2], b0.z), 0.f) * dv;
        r[3] = fmaxf(fmaf(dv, u[3], b0.w), 0.f) * dv;
        r[4] = fmaxf(fmaf(dv, u[4], b1.x), 0.f) * dv;
        r[5] = fmaxf(fmaf(dv, u[5], b1.y), 0.f) * dv;
        r[6] = fmaxf(fmaf(dv, u[6], b1.z), 0.f) * dv;
        r[7] = fmaxf(fmaf(dv, u[7], b1.w), 0.f) * dv;
        zout[(size_t)node * 8 + c] = f8_to_h8(r);    // z_{l+1}
    }
}

// ---------------------------------------------------------------------------
// Final: s = gather(z2); h = relu(dis*(s@W2)+b2); out = h @ linW + linb.
// Second mm: lane c computes output col c (all 8 lanes active).
// ---------------------------------------------------------------------------
__global__ __launch_bounds__(TPB) void layer_final(const u16x8* __restrict__ z,
                                                   const int* __restrict__ csr,
                                                   const int2* __restrict__ meta,
                                                   const float* __restrict__ b,
                                                   const float* __restrict__ W,
                                                   const float* __restrict__ Wl,
                                                   const float* __restrict__ bl,
                                                   float* __restrict__ out, int n) {
    __shared__ float Ws[64 * 64];
    __shared__ float Wls[64 * 8];
    __shared__ float bls[8];
    int t = threadIdx.x;
    float4* Ws4 = (float4*)Ws;
    const float4* W4g = (const float4*)W;
    #pragma unroll
    for (int i = 0; i < 4; ++i) Ws4[t + i * TPB] = W4g[t + i * TPB];
    if (t < 128) ((float4*)Wls)[t] = ((const float4*)Wl)[t];
    if (t < 8) bls[t] = bl[t];

    int wave = t >> 6, lane = t & 63;
    int g = lane >> 3, c = lane & 7;
    int node = blockIdx.x * 32 + wave * 8 + g;
    f32x8 s = {0.f, 0.f, 0.f, 0.f, 0.f, 0.f, 0.f, 0.f};
    float dv = 0.f;
    if (node < n) {
        int2 m = meta[node];
        int start = ((unsigned)m.x) >> 8;
        int nbatch = m.x & 255;
        dv = __int_as_float(m.y);
        u16x8 v = z[(size_t)node * 8 + c];
        #pragma unroll
        for (int i = 0; i < 8; ++i) s[i] = __half2float(__ushort_as_half(v[i]));
        s = gather_rows(z, csr, start, nbatch, c, s);
    }
    __syncthreads();                             // Ws/Wls/bls staged
    f32x8 u = shfl_mm8(s, Ws4, c);
    float4 b0 = ((const float4*)b)[2 * c];
    float4 b1 = ((const float4*)b)[2 * c + 1];
    f32x8 h;
    h[0] = fmaxf(fmaf(dv, u[0], b0.x), 0.f);
    h[1] = fmaxf(fmaf(dv, u[1], b0.y), 0.f);
    h[2] = fmaxf(fmaf(dv, u[2], b0.z), 0.f);
    h[3] = fmaxf(fmaf(dv, u[3], b0.w), 0.f);
    h[4] = fmaxf(fmaf(dv, u[4], b1.x), 0.f);
    h[5] = fmaxf(fmaf(dv, u[5], b1.y), 0.f);
    h[6] = fmaxf(fmaf(dv, u[6], b1.z), 0.f);
    h[7] = fmaxf(fmaf(dv, u[7], b1.w), 0.f);

    // second mm (64 -> 8): lane c computes output col c.
    const int base = threadIdx.x & 56;
    float acc = bls[c];
    #pragma unroll
    for (int q = 0; q < 8; ++q) {
        #pragma unroll
        for (int r = 0; r < 8; ++r) {
            float hv = __shfl(h[r], base + q);   // feature q*8+r
            acc = fmaf(hv, Wls[(q * 8 + r) * 8 + c], acc);
        }
    }
    if (node < n) out[(size_t)node * 8 + c] = acc;
}

extern "C" void kernel_launch(void* const* d_in, const int* in_sizes, int n_in,
                              void* d_out, int out_size, void* d_ws, size_t ws_size,
                              hipStream_t stream) {
    const float* x  = (const float*)d_in[0];
    const void*  ei = d_in[1];
    const float* W0 = (const float*)d_in[2];
    const float* b0 = (const float*)d_in[3];
    const float* W1 = (const float*)d_in[4];
    const float* b1 = (const float*)d_in[5];
    const float* W2 = (const float*)d_in[6];
    const float* b2 = (const float*)d_in[7];
    const float* Wl = (const float*)d_in[8];
    const float* bl = (const float*)d_in[9];

    const long long E = in_sizes[1] / 2;                 // 800000
    const int dh = in_sizes[3];                          // 64
    const int din = in_sizes[2] / dh;                    // 64
    const int N = in_sizes[0] / din;                     // 50000
    const int nb = (N + 255) >> 8;                       // 196 buckets

    // Workspace carve (256-aligned): ~39 MB total
    char* ws = (char*)d_ws;
    size_t off = 0;
    auto alloc = [&](size_t bytes) -> char* {
        char* r = ws + off;
        off += (bytes + 255) & ~(size_t)255;
        return r;
    };
    int*   gcur    = (int*)  alloc(1024);
    int2*  meta    = (int2*) alloc((size_t)N * 8);
    int*   pairs   = (int*)  alloc((size_t)nb * CAP * 4);       // 12.8 MB
    int*   csr     = (int*)  alloc((size_t)nb * CAP * 4);       // 12.8 MB
    u16x8* zbA     = (u16x8*)alloc((size_t)(N + 1) * 64 * 2);   // fp16 rows (+zero row)
    u16x8* zbB     = (u16x8*)alloc((size_t)(N + 1) * 64 * 2);

    // --- preprocessing ---
    hipMemsetAsync(gcur, 0, 256 * sizeof(int), stream);
    p3_scatter<<<SC_BLOCKS, TPB, 0, stream>>>(ei, E, gcur, pairs);
    p4_fill<<<nb, TPB, 0, stream>>>(pairs, gcur, x, meta, csr,
                                    (ushort4*)zbA, N);

    // --- 3 layers: gather -> mm -> relu ---
    const int gL = (N + 31) / 32;                        // 1563
    layer_mm<<<gL, TPB, 0, stream>>>(zbA, csr, meta, b0, W0, zbB, N);
    layer_mm<<<gL, TPB, 0, stream>>>(zbB, csr, meta, b1, W1, zbA, N);
    layer_final<<<gL, TPB, 0, stream>>>(zbA, csr, meta, b2, W2, Wl, bl,
                                        (float*)d_out, N);
}